// Round 3
// baseline (528.046 us; speedup 1.0000x reference)
//
#include <hip/hip_runtime.h>

// Output: (1, 8, 4096, 4096) float32, 512 MiB. Pure write-BW bound.
//   plane c in [0,4):  out[c,i,j] = table[seq[i]*4 + c]      -> constant per row
//   plane c in [4,8):  out[c,i,j] = table[seq[j]*4 + (c-4)]  -> identical row repeated over i
//
// R0-R2 lessons: one-store/thread vs 16-store/thread, NT vs plain stores all
// NEUTRAL at ~2.9 TB/s writes, while rocclr fillBuffer hits 6.3 TB/s at 10%
// occupancy (small persistent grid, grid-stride, compact sliding write window).
// This round: mimic the fill's shape. Persistent grid, 1024 blocks
// (8 planes x 128 slots), each block strides over its plane's rows ->
// 128 f4 stores/thread, 8 compact 2-MiB windows sweeping linearly.

#define L 4096
#define BPP 128u                     // blocks per plane
#define ROWS_PER_BLOCK (L / BPP)     // 32
#define ROW_F4 (L / 4)               // 1024 float4 per row
#define PLANE_F4 (L * (L / 4))       // 4,194,304 float4 per plane

typedef float v4f __attribute__((ext_vector_type(4)));
typedef int   v4i __attribute__((ext_vector_type(4)));

__global__ __launch_bounds__(256) void SequenceEmbedding_30923764532139_kernel(
        const int* __restrict__ seq,
        const float* __restrict__ table,
        v4f* __restrict__ out) {
    const unsigned bid   = blockIdx.x;
    const unsigned plane = bid >> 7;           // 0..7   (uniform per block)
    const unsigned slot  = bid & (BPP - 1u);   // 0..127 (uniform per block)
    const unsigned t     = threadIdx.x;        // 0..255

    v4f* pbase = out + (size_t)plane * PLANE_F4;

    if (plane < 4u) {
        // Row-constant planes: one (wave-uniform) table value per row,
        // broadcast along j. 4 f4 stores/thread/row.
#pragma unroll 4
        for (unsigned r = 0; r < ROWS_PER_BLOCK; ++r) {
            const unsigned row = slot + r * BPP;
            const float x = table[(unsigned)seq[row] * 4u + plane];
            const v4f val = (v4f){x, x, x, x};
            v4f* rowp = pbase + (size_t)row * ROW_F4 + t;
#pragma unroll
            for (int k = 0; k < 4; ++k)
                rowp[(unsigned)k * 256u] = val;
        }
    } else {
        // Column-pattern planes: row vector depends only on j; compute this
        // thread's 4 float4 slices ONCE, then replay as pure stores.
        const unsigned cc = plane - 4u;
        v4f vals[4];
#pragma unroll
        for (int k = 0; k < 4; ++k) {
            const unsigned j = (unsigned)k * 1024u + t * 4u;   // float index
            const v4i s = *(const v4i*)(seq + j);              // 16B aligned
            vals[k].x = table[(unsigned)s.x * 4u + cc];
            vals[k].y = table[(unsigned)s.y * 4u + cc];
            vals[k].z = table[(unsigned)s.z * 4u + cc];
            vals[k].w = table[(unsigned)s.w * 4u + cc];
        }

#pragma unroll 4
        for (unsigned r = 0; r < ROWS_PER_BLOCK; ++r) {
            const unsigned row = slot + r * BPP;
            v4f* rowp = pbase + (size_t)row * ROW_F4 + t;
#pragma unroll
            for (int k = 0; k < 4; ++k)
                rowp[(unsigned)k * 256u] = vals[k];
        }
    }
}

extern "C" void kernel_launch(void* const* d_in, const int* in_sizes, int n_in,
                              void* d_out, int out_size, void* d_ws, size_t ws_size,
                              hipStream_t stream) {
    const int*   seq   = (const int*)d_in[0];
    const float* table = (const float*)d_in[1];
    v4f*         out   = (v4f*)d_out;

    dim3 block(256);
    dim3 grid(8u * BPP);   // 1024 persistent blocks, exact cover
    SequenceEmbedding_30923764532139_kernel<<<grid, block, 0, stream>>>(seq, table, out);
}